// Round 3
// baseline (82.173 us; speedup 1.0000x reference)
//
#include <hip/hip_runtime.h>

constexpr int H = 512, W = 512;   // fixed by the problem (4,3,512,512)
constexpr int K = 5, PADR = 2;
constexpr int TR = 2;             // output rows per block
constexpr int SR = TR + 4;        // staged input rows (r0-2 .. r0+3)

__device__ __forceinline__ float rfl(float v) {
    union { float f; int i; } u; u.f = v;
    u.i = __builtin_amdgcn_readfirstlane(u.i);
    return u.f;
}

// map squared spatial distance {0,1,2,4,5,8} -> compact index 0..5
constexpr int idx6(int d2) {
    return d2 == 0 ? 0 : d2 == 1 ? 1 : d2 == 2 ? 2 : d2 == 4 ? 3 : d2 == 5 ? 4 : 5;
}

// 4 px/lane, contiguous mapping: lane owns cols 4c..4c+3, so every
// ds_read_b128 / ds_write_b128 has lane-stride 16 B = conflict-free (the
// previous 8 px/lane layout was a 16-way LDS bank conflict on all 20 window
// reads: lane stride 32 B aliases lanes {l,l+4,...} onto one bank quad).
// Block = 2 output rows x 512 cols (wave = half row), 6 input rows in 12 KB
// LDS. Math fully scalar: tap reads win[p+j] are direct register refs.
__global__ __launch_bounds__(256, 4) void bilateral_kernel(
    const float* __restrict__ x,
    const float* __restrict__ sk,
    const float* __restrict__ sigma_color,
    float* __restrict__ out)
{
    __shared__ float lds[SR][W];      // 12 KB

    int t = threadIdx.x;
    int wv = t >> 6;
    int l = t & 63;

    // 6 distinct spatial weights by symmetry: d2 = {0,1,2,4,5,8} at flat
    // positions {12, 7, 6, 2, 1, 0}. log2 once, broadcast to SGPRs.
    float lw[6];
    lw[0] = rfl(__builtin_amdgcn_logf(sk[12]));
    lw[1] = rfl(__builtin_amdgcn_logf(sk[7]));
    lw[2] = rfl(__builtin_amdgcn_logf(sk[6]));
    lw[3] = rfl(__builtin_amdgcn_logf(sk[2]));
    lw[4] = rfl(__builtin_amdgcn_logf(sk[1]));
    lw[5] = rfl(__builtin_amdgcn_logf(sk[0]));
    float sk12 = rfl(sk[12]);         // center tap weight, exact (exp(0)=1)

    float s = sigma_color[0];                          // wave-uniform
    float c2 = -1.4426950408889634f / (2.0f * s * s);  // -log2(e)/(2s^2)

    int plane = blockIdx.x >> 8;           // 12 planes (B*C)
    int r0 = (blockIdx.x & 255) << 1;      // first output row of tile
    const float* xp = x + (size_t)plane * (H * W);

    // ---- stage 6 rows x 512 cols as 12 (row,half) units, 3 per wave.
    // Each unit: 64 lanes x float4, global coalesced, LDS write stride 16 B.
#pragma unroll
    for (int su = 0; su < 3; ++su) {
        int u = wv + (su << 2);            // 0..11
        int k = u >> 1, hh = u & 1;
        int gr = r0 - 2 + k;               // np 'reflect': -1 -> 1, H -> H-2
        gr = (gr < 0) ? -gr : gr;
        gr = (gr >= H) ? (2 * H - 2 - gr) : gr;
        int col = (hh << 8) + (l << 2);
        float4 v = *(const float4*)(xp + (gr << 9) + col);
        *(float4*)(&lds[k][col]) = v;
    }
    __syncthreads();

    // ---- compute: wave wv -> output row r0+(wv>>1), chunk c = cols 4c..4c+3
    int rr = wv >> 1;
    int c  = ((wv & 1) << 6) + l;          // 0..127
    bool le = (c == 0), re = (c == 127);   // image edge chunks
    int cm1 = le ? 0   : c - 1;
    int cp1 = re ? 127 : c + 1;

    float cc[4], wsum[4], acc[4];
#pragma unroll
    for (int p = 0; p < 4; ++p) { wsum[p] = 0.f; acc[p] = 0.f; }

    constexpr int order[K] = {2, 0, 1, 3, 4};   // center row first -> cc ready
#pragma unroll
    for (int oi = 0; oi < K; ++oi) {
        const int i = order[oi];
        const float* rp = &lds[rr + i][0];

        float4 a = *(const float4*)(rp + (cm1 << 2));
        float4 m = *(const float4*)(rp + (c   << 2));
        float4 b = *(const float4*)(rp + (cp1 << 2));

        // window cols 4c-2 .. 4c+5
        float win[8];
        win[0] = le ? m.z : a.z;           // col -2 -> 2 at left edge
        win[1] = le ? m.y : a.w;           // col -1 -> 1
        win[2] = m.x; win[3] = m.y; win[4] = m.z; win[5] = m.w;
        win[6] = re ? m.z : b.x;           // col 512 -> 510 at right edge
        win[7] = re ? m.y : b.y;           // col 513 -> 509

        if (oi == 0) {                     // i==2: capture center pixels
#pragma unroll
            for (int p = 0; p < 4; ++p) cc[p] = win[p + 2];
        }

#pragma unroll
        for (int j = 0; j < K; ++j) {
            if (i == 2 && j == 2) {
                // center tap: d=0, weight = sk[12] exactly
#pragma unroll
                for (int p = 0; p < 4; ++p) {
                    wsum[p] += sk12;
                    acc[p] = __builtin_fmaf(sk12, cc[p], acc[p]);
                }
            } else {
                const float lwv = lw[idx6((i - 2) * (i - 2) + (j - 2) * (j - 2))];
#pragma unroll
                for (int p = 0; p < 4; ++p) {
                    float v = win[p + j];
                    float d = v - cc[p];
                    float arg = __builtin_fmaf(d * c2, d, lwv);
                    float wq = __builtin_amdgcn_exp2f(arg);
                    wsum[p] += wq;
                    acc[p] = __builtin_fmaf(wq, v, acc[p]);
                }
            }
        }
    }

    float* op = out + (size_t)plane * (H * W) + ((size_t)(r0 + rr) << 9) + (c << 2);
    float4 o;
    o.x = acc[0] * __builtin_amdgcn_rcpf(wsum[0] + 1e-8f);
    o.y = acc[1] * __builtin_amdgcn_rcpf(wsum[1] + 1e-8f);
    o.z = acc[2] * __builtin_amdgcn_rcpf(wsum[2] + 1e-8f);
    o.w = acc[3] * __builtin_amdgcn_rcpf(wsum[3] + 1e-8f);
    *(float4*)op = o;
}

extern "C" void kernel_launch(void* const* d_in, const int* in_sizes, int n_in,
                              void* d_out, int out_size, void* d_ws, size_t ws_size,
                              hipStream_t stream) {
    const float* x  = (const float*)d_in[0];
    const float* sk = (const float*)d_in[1];
    const float* sc = (const float*)d_in[2];
    float* out = (float*)d_out;

    const int total = in_sizes[0];              // 3,145,728 elements
    const int blocks = total / (256 * 4);       // 3072 = 12 planes * 256 tiles
    bilateral_kernel<<<blocks, 256, 0, stream>>>(x, sk, sc, out);
}